// Round 1
// baseline (349.596 us; speedup 1.0000x reference)
//
#include <hip/hip_runtime.h>

// RunningCenters R7: occupancy round.
//  - class_sum: 512 threads (8 waves) per class block -> ~31 waves/CU
//    (was 4 waves x 1000 blocks ~ 15/CU). Same unroll-8 NT gather.
//  - hist/scatter: BS 128->256 blocks, TS 512 -> 131k threads (was 65k).
//  - colscan: unroll 16 (batch 16 independent column loads before the
//    serial running-sum writes) -> 4x memory-level parallelism.
// Semantics identical to R6 (measured 348.0us).

constexpr int C = 1000;
constexpr int D = 128;
constexpr int BS = 256;    // sort blocks
constexpr int TS = 512;    // sort threads/block
constexpr int TILE = 2048; // idx staging tile (8 KB LDS)
constexpr int CST = 512;   // class_sum threads (8 waves)

typedef float f4 __attribute__((ext_vector_type(4)));

// ws layout (all regions fully written before read; poison-safe, no memset):
// counts  u32[1024]    @ 0
// offsets u32[1032]    @ 4096
// hist    u32[BS*C]    @ 8192        (1 MB; becomes blockBase in-place)
// sorted  int[N]       @ 8192 + BS*C*4

__global__ __launch_bounds__(TS) void hist_kernel(
    const int* __restrict__ y, unsigned int* __restrict__ hist,
    int N, int chunk) {
  __shared__ unsigned int h[C];
  for (int t = threadIdx.x; t < C; t += TS) h[t] = 0u;
  __syncthreads();
  const int b = blockIdx.x;
  const int beg = b * chunk;
  const int e = min(beg + chunk, N);
  for (int i = beg + threadIdx.x; i < e; i += TS) atomicAdd(&h[y[i]], 1u);
  __syncthreads();
  for (int t = threadIdx.x; t < C; t += TS) hist[b * C + t] = h[t];
}

__global__ __launch_bounds__(64) void colscan_kernel(
    unsigned int* __restrict__ hist, unsigned int* __restrict__ counts) {
  const int c = blockIdx.x * 64 + threadIdx.x;
  if (c >= C) return;
  unsigned int run = 0;
  for (int b = 0; b < BS; b += 16) {   // BS=256 -> exactly 16 iterations
    unsigned int v[16];
#pragma unroll
    for (int k = 0; k < 16; ++k) v[k] = hist[(b + k) * C + c];
#pragma unroll
    for (int k = 0; k < 16; ++k) {
      hist[(b + k) * C + c] = run;
      run += v[k];
    }
  }
  counts[c] = run;
}

__global__ __launch_bounds__(1024) void scan_kernel(
    const unsigned int* __restrict__ counts,
    unsigned int* __restrict__ offsets) {
  __shared__ unsigned int buf[2][1024];
  const int t = threadIdx.x;
  unsigned int v = (t < C) ? counts[t] : 0u;
  buf[0][t] = v;
  __syncthreads();
  int s = 0;
  for (int off = 1; off < 1024; off <<= 1) {
    unsigned int u = buf[s][t];
    if (t >= off) u += buf[s][t - off];
    buf[1 - s][t] = u;
    s = 1 - s;
    __syncthreads();
  }
  if (t < C) {
    unsigned int incl = buf[s][t];
    offsets[t] = incl - v;
    if (t == C - 1) offsets[C] = incl;
  }
}

__global__ __launch_bounds__(TS) void scatter_kernel(
    const int* __restrict__ y, const unsigned int* __restrict__ hist,
    const unsigned int* __restrict__ offsets, int* __restrict__ sorted,
    int N, int chunk) {
  __shared__ unsigned int cur[C];
  const int b = blockIdx.x;
  for (int t = threadIdx.x; t < C; t += TS)
    cur[t] = offsets[t] + hist[b * C + t];
  __syncthreads();
  const int beg = b * chunk;
  const int e = min(beg + chunk, N);
  for (int i = beg + threadIdx.x; i += 0, i < e; i += TS) {
    int c = y[i];
    unsigned int pos = atomicAdd(&cur[c], 1u);
    sorted[pos] = i;
  }
}

// One block (8 waves) per class. Indices staged in LDS; each wave-load
// covers 2 rows (lane>>5 picks row of pair, lane&31 picks float4 of row).
// Unroll 8, non-temporal x loads.
__global__ __launch_bounds__(CST) void class_sum_kernel(
    const float* __restrict__ x, const int* __restrict__ sorted,
    const unsigned int* __restrict__ offsets,
    const float* __restrict__ centers, const float* __restrict__ counter,
    float* __restrict__ out) {
  const int c = blockIdx.x;
  const int begin = (int)offsets[c];
  const int n = (int)offsets[c + 1] - begin;
  const int wave = threadIdx.x >> 6;  // 0..7
  const int lane = threadIdx.x & 63;
  const int half = lane >> 5;   // which row of the pair
  const int d4 = lane & 31;     // which float4 within the row

  __shared__ int idx[TILE];
  __shared__ f4 red[8][64];
  f4 acc = (f4)(0.f);

  for (int t0 = 0; t0 < n; t0 += TILE) {
    const int nt = min(TILE, n - t0);
    __syncthreads();
    for (int t = threadIdx.x; t < nt; t += CST) idx[t] = sorted[begin + t0 + t];
    __syncthreads();
    const int npair = nt >> 1;
    int q = wave;
    for (; q + 56 < npair; q += 64) {  // unroll 8: 8 x 1KB loads in flight
#pragma unroll
      for (int u = 0; u < 8; ++u) {
        const int p = (q + 8 * u) * 2 + half;
        f4 v = __builtin_nontemporal_load(
            (const f4*)(x + (size_t)idx[p] * D) + d4);
        acc += v;
      }
    }
    for (; q < npair; q += 8) {
      const int p = q * 2 + half;
      f4 v = __builtin_nontemporal_load(
          (const f4*)(x + (size_t)idx[p] * D) + d4);
      acc += v;
    }
    if ((nt & 1) && wave == 0 && half == 0) {  // odd tail point, lanes 0-31
      f4 v = __builtin_nontemporal_load(
          (const f4*)(x + (size_t)idx[nt - 1] * D) + d4);
      acc += v;
    }
  }

  red[wave][lane] = acc;
  __syncthreads();
  if (threadIdx.x < 32) {
    const int l = threadIdx.x;
    f4 s = (f4)(0.f);
#pragma unroll
    for (int w = 0; w < 8; ++w) s += red[w][l] + red[w][l + 32];
    const f4 cen = ((const f4*)centers)[c * 32 + l];
    f4 o;
    if (n > 0) {
      const float k = counter[0];
      const float inv = 1.f / (float)n;
      const float ik = 1.f / (k + 1.f);
      o = (s * inv + cen * k) * ik;
    } else {
      o = cen;
    }
    ((f4*)out)[c * 32 + l] = o;
  }
}

extern "C" void kernel_launch(void* const* d_in, const int* in_sizes, int n_in,
                              void* d_out, int out_size, void* d_ws, size_t ws_size,
                              hipStream_t stream) {
  const float* x       = (const float*)d_in[0];
  const int* y         = (const int*)d_in[1];
  const float* centers = (const float*)d_in[2];
  const float* counter = (const float*)d_in[3];
  float* out = (float*)d_out;
  const int N = in_sizes[1];

  unsigned int* counts  = (unsigned int*)d_ws;
  unsigned int* offsets = (unsigned int*)((char*)d_ws + 4096);
  unsigned int* hist    = (unsigned int*)((char*)d_ws + 8192);
  int* sorted           = (int*)((char*)d_ws + 8192 + (size_t)BS * C * 4);

  const int chunk = (N + BS - 1) / BS;

  hist_kernel<<<dim3(BS), dim3(TS), 0, stream>>>(y, hist, N, chunk);
  colscan_kernel<<<dim3(16), dim3(64), 0, stream>>>(hist, counts);
  scan_kernel<<<dim3(1), dim3(1024), 0, stream>>>(counts, offsets);
  scatter_kernel<<<dim3(BS), dim3(TS), 0, stream>>>(y, hist, offsets, sorted,
                                                    N, chunk);
  class_sum_kernel<<<dim3(C), dim3(CST), 0, stream>>>(x, sorted, offsets,
                                                      centers, counter, out);
}